// Round 1
// baseline (2109.819 us; speedup 1.0000x reference)
//
#include <hip/hip_runtime.h>
#include <cstddef>

#define SLEN 1024
#define DIM  768
#define NJ   32
#define KSPEC (NJ * DIM)          // 24576 spectral K-columns (32 filters x 768)
#define KTOT  (KSPEC + 3 * DIM)   // 26880 = spectral + 3-tap ar_u
#define MROWS (2 * SLEN)          // 2048 = B*SL
#define SPLITK 4
#define KCHUNK (KTOT / SPLITK)    // 6720 = 420 tiles of 16

// ---------------------------------------------------------------------------
// F[j][tau], j in [0,32): j<16 -> sigma[k]^0.25 * V[tau,k]
//                         j>=16 -> sigma[k]^0.25 * (-1)^tau * V[tau,k]
// (sign-alternation of the minus branch folded into the filter)
// ---------------------------------------------------------------------------
__global__ __launch_bounds__(256) void build_filters(
    const float* __restrict__ sigma, const float* __restrict__ V,
    float* __restrict__ F)
{
    int g = blockIdx.x * 256 + threadIdx.x;   // 0..32767
    int j = g >> 10, tau = g & 1023;
    int k = j & 15;
    float s = powf(sigma[k], 0.25f);
    float val = s * V[tau * 16 + k];
    if (j >= 16 && (tau & 1)) val = -val;
    F[j * SLEN + tau] = val;
}

// ---------------------------------------------------------------------------
// Causal conv: U[b][l][j*768+d] = sum_{t<=l} F[j][l-t] * x[b][t][d]
// Block: one (b, j), 128 l-rows x 64 d-cols. Per-thread 8x4 micro-tile.
// F segment cached in 23 registers per thread (5.6x LDS-read reuse).
// ---------------------------------------------------------------------------
__global__ __launch_bounds__(256) void conv_kernel(
    const float* __restrict__ x, const float* __restrict__ F,
    float* __restrict__ U)
{
    __shared__ float xs[16][64];
    __shared__ float Fs[160];
    const int b  = blockIdx.z >> 5;
    const int j  = blockIdx.z & 31;
    const int l0 = blockIdx.y * 128;
    const int d0 = blockIdx.x * 64;
    const int tid = threadIdx.x;
    const int td = tid & 15, tl = tid >> 4;

    float acc[8][4];
#pragma unroll
    for (int i = 0; i < 8; ++i)
#pragma unroll
        for (int q = 0; q < 4; ++q) acc[i][q] = 0.f;

    const float* Fj = F + j * SLEN;
    const int ntile = (l0 >> 4) + 8;          // t-tiles with t0 <= l0+127
    const int xrow = tid >> 4, xcol = (tid & 15) * 4;

    for (int tt0 = 0; tt0 < ntile; ++tt0) {
        const int t0 = tt0 * 16;
        *(float4*)&xs[xrow][xcol] =
            *(const float4*)&x[(size_t)((b * SLEN + t0 + xrow) * DIM) + d0 + xcol];
        if (tid < 144) {                      // tau range [l0-t0-15, l0-t0+128]
            int tau = l0 - t0 - 15 + tid;
            Fs[tid] = (tau >= 0 && tau < SLEN) ? Fj[tau] : 0.f;  // tau<0 => t>l (causal zero)
        }
        __syncthreads();
        float fv[23];
#pragma unroll
        for (int m = 0; m < 23; ++m) fv[m] = Fs[tl * 8 + m];
#pragma unroll
        for (int tt = 0; tt < 16; ++tt) {
            float4 bv = *(float4*)&xs[tt][td * 4];
#pragma unroll
            for (int i = 0; i < 8; ++i) {
                float a = fv[i + 15 - tt];    // = F[j][(l0+tl*8+i) - (t0+tt)]
                acc[i][0] = fmaf(a, bv.x, acc[i][0]);
                acc[i][1] = fmaf(a, bv.y, acc[i][1]);
                acc[i][2] = fmaf(a, bv.z, acc[i][2]);
                acc[i][3] = fmaf(a, bv.w, acc[i][3]);
            }
        }
        __syncthreads();
    }
#pragma unroll
    for (int i = 0; i < 8; ++i) {
        int l = l0 + tl * 8 + i;
        float4 v = make_float4(acc[i][0], acc[i][1], acc[i][2], acc[i][3]);
        *(float4*)&U[(size_t)(b * SLEN + l) * KSPEC + j * DIM + d0 + td * 4] = v;
    }
}

// ---------------------------------------------------------------------------
// gemm1: P[s][m][o] = partial_K  X[m][c] * W[c][o]
//  X[m=b*1024+l, c]:  c<24576 -> U[b][l-2][c]   (spectral, shift-by-2, 0 if l<2)
//                     c>=24576 -> inputs[b][l-i][d], i=(c-24576)/768 (ar_u taps)
//  W rows: c<12288 -> M_phi_plus, <24576 -> M_phi_minus, else -> M_u (all (kd)xO row-major)
// 128x64 tile, per-thread 8x4, split-K=4 deterministic partials.
// ---------------------------------------------------------------------------
__global__ __launch_bounds__(256) void gemm1_kernel(
    const float* __restrict__ U, const float* __restrict__ x,
    const float* __restrict__ Mpp, const float* __restrict__ Mpm,
    const float* __restrict__ Mu, float* __restrict__ P)
{
    __shared__ float As[128][20];   // pad 16->20: aligned float4 stores, spread banks
    __shared__ float Bs[16][64];
    const int n0 = blockIdx.x * 64;
    const int m0 = blockIdx.y * 128;
    const int s  = blockIdx.z;
    const int tid = threadIdx.x;
    const int td = tid & 15, tl = tid >> 4;

    float acc[8][4];
#pragma unroll
    for (int i = 0; i < 8; ++i)
#pragma unroll
        for (int q = 0; q < 4; ++q) acc[i][q] = 0.f;

    const int ar = tid >> 1;           // A row 0..127
    const int ac = (tid & 1) * 8;      // A col offset 0/8
    const int m  = m0 + ar;
    const int l  = m & (SLEN - 1);
    const int brow = tid >> 4;         // B row 0..15
    const int bcol = (tid & 15) * 4;   // B col

    const int c_end = (s + 1) * KCHUNK;
    for (int c0 = s * KCHUNK; c0 < c_end; c0 += 16) {
        float4 a0 = make_float4(0.f,0.f,0.f,0.f), a1 = a0;
        if (c0 < KSPEC) {
            if (l >= 2) {
                const float* src = U + (size_t)(m - 2) * KSPEC + c0 + ac;
                a0 = *(const float4*)src;
                a1 = *(const float4*)(src + 4);
            }
        } else {
            int cr = c0 - KSPEC;
            int i  = cr / DIM;                       // tap 0..2 (tile-uniform)
            if (l >= i) {
                const float* src = x + (size_t)(m - i) * DIM + (cr - i * DIM) + ac;
                a0 = *(const float4*)src;
                a1 = *(const float4*)(src + 4);
            }
        }
        *(float4*)&As[ar][ac]     = a0;
        *(float4*)&As[ar][ac + 4] = a1;

        const float* bp;
        if (c0 < 12288)      bp = Mpp + (size_t)c0 * DIM;
        else if (c0 < KSPEC) bp = Mpm + (size_t)(c0 - 12288) * DIM;
        else                 bp = Mu  + (size_t)(c0 - KSPEC) * DIM;
        *(float4*)&Bs[brow][bcol] =
            *(const float4*)(bp + (size_t)brow * DIM + n0 + bcol);

        __syncthreads();
#pragma unroll
        for (int kk = 0; kk < 16; ++kk) {
            float a[8];
#pragma unroll
            for (int i = 0; i < 8; ++i) a[i] = As[tl * 8 + i][kk];
            float4 bv = *(float4*)&Bs[kk][td * 4];
#pragma unroll
            for (int i = 0; i < 8; ++i) {
                acc[i][0] = fmaf(a[i], bv.x, acc[i][0]);
                acc[i][1] = fmaf(a[i], bv.y, acc[i][1]);
                acc[i][2] = fmaf(a[i], bv.z, acc[i][2]);
                acc[i][3] = fmaf(a[i], bv.w, acc[i][3]);
            }
        }
        __syncthreads();
    }
    float* Pp = P + (size_t)s * MROWS * DIM;
#pragma unroll
    for (int i = 0; i < 8; ++i) {
        *(float4*)&Pp[(size_t)(m0 + tl * 8 + i) * DIM + n0 + td * 4] =
            make_float4(acc[i][0], acc[i][1], acc[i][2], acc[i][3]);
    }
}

// z = sum of 4 split-K partials (deterministic)
__global__ __launch_bounds__(256) void reduce_kernel(
    const float* __restrict__ P, float* __restrict__ z)
{
    int g = blockIdx.x * 256 + threadIdx.x;   // 0..393215 float4s
    const float4* P4 = (const float4*)P;
    float4 a = P4[g];
    float4 b = P4[g + 393216];
    float4 c = P4[g + 786432];
    float4 d = P4[g + 1179648];
    ((float4*)z)[g] = make_float4(a.x + b.x + c.x + d.x,
                                  a.y + b.y + c.y + d.y,
                                  a.z + b.z + c.z + d.z,
                                  a.w + b.w + c.w + d.w);
}

// ---------------------------------------------------------------------------
// gemm2: out[m][o] = z[m][o] + sum_{i=0,1} sum_d z[b][l-1-i][d] * M_y[o][i][d]
// A read from z with row shifts; B = M_y accessed as [o*1536 + c] (transposed).
// 64x128 tile, per-thread 4x8.
// ---------------------------------------------------------------------------
__global__ __launch_bounds__(256) void gemm2_kernel(
    const float* __restrict__ z, const float* __restrict__ My,
    float* __restrict__ out)
{
    __shared__ float As[64][20];
    __shared__ float Bs[16][128];
    const int n0 = blockIdx.x * 128;
    const int m0 = blockIdx.y * 64;
    const int tid = threadIdx.x;
    const int td = tid & 15, tl = tid >> 4;

    float acc[4][8];
#pragma unroll
    for (int i = 0; i < 4; ++i)
#pragma unroll
        for (int q = 0; q < 8; ++q) acc[i][q] = 0.f;

    const int ar = tid >> 2;          // 0..63
    const int ac = (tid & 3) * 4;     // 0,4,8,12
    const int m  = m0 + ar;
    const int l  = m & (SLEN - 1);
    const int bcc = tid & 15;
    const int bo  = (tid >> 4) * 8;

    for (int c0 = 0; c0 < 1536; c0 += 16) {
        int i = (c0 >= DIM) ? 1 : 0;  // tap index (tile-uniform)
        float4 a0 = make_float4(0.f,0.f,0.f,0.f);
        if (l >= i + 1)
            a0 = *(const float4*)&z[(size_t)(m - 1 - i) * DIM + (c0 - i * DIM) + ac];
        *(float4*)&As[ar][ac] = a0;
#pragma unroll
        for (int u = 0; u < 8; ++u)
            Bs[bcc][bo + u] = My[(size_t)(n0 + bo + u) * 1536 + c0 + bcc];
        __syncthreads();
#pragma unroll
        for (int kk = 0; kk < 16; ++kk) {
            float a[4];
#pragma unroll
            for (int i2 = 0; i2 < 4; ++i2) a[i2] = As[tl * 4 + i2][kk];
            float4 b0 = *(float4*)&Bs[kk][td * 8];
            float4 b1 = *(float4*)&Bs[kk][td * 8 + 4];
#pragma unroll
            for (int i2 = 0; i2 < 4; ++i2) {
                acc[i2][0] = fmaf(a[i2], b0.x, acc[i2][0]);
                acc[i2][1] = fmaf(a[i2], b0.y, acc[i2][1]);
                acc[i2][2] = fmaf(a[i2], b0.z, acc[i2][2]);
                acc[i2][3] = fmaf(a[i2], b0.w, acc[i2][3]);
                acc[i2][4] = fmaf(a[i2], b1.x, acc[i2][4]);
                acc[i2][5] = fmaf(a[i2], b1.y, acc[i2][5]);
                acc[i2][6] = fmaf(a[i2], b1.z, acc[i2][6]);
                acc[i2][7] = fmaf(a[i2], b1.w, acc[i2][7]);
            }
        }
        __syncthreads();
    }
#pragma unroll
    for (int i = 0; i < 4; ++i) {
        int mm = m0 + tl * 4 + i;
        const float* zr = z + (size_t)mm * DIM + n0 + td * 8;
        float4 z0 = *(const float4*)zr;
        float4 z1 = *(const float4*)(zr + 4);
        float* orow = out + (size_t)mm * DIM + n0 + td * 8;
        *(float4*)orow =
            make_float4(acc[i][0] + z0.x, acc[i][1] + z0.y,
                        acc[i][2] + z0.z, acc[i][3] + z0.w);
        *(float4*)(orow + 4) =
            make_float4(acc[i][4] + z1.x, acc[i][5] + z1.y,
                        acc[i][6] + z1.z, acc[i][7] + z1.w);
    }
}

extern "C" void kernel_launch(void* const* d_in, const int* in_sizes, int n_in,
                              void* d_out, int out_size, void* d_ws, size_t ws_size,
                              hipStream_t stream)
{
    const float* inputs = (const float*)d_in[0];   // (2,1024,768)
    const float* sigma  = (const float*)d_in[1];   // (16,)
    const float* V      = (const float*)d_in[2];   // (1024,16)
    const float* Mu     = (const float*)d_in[3];   // (3,768,768)
    const float* Mpp    = (const float*)d_in[4];   // (16,768,768)
    const float* Mpm    = (const float*)d_in[5];   // (16,768,768)
    const float* My     = (const float*)d_in[6];   // (768,2,768)
    // d_in[7] = padded_sl (2048) — semantics hardcoded (causal conv, no wraparound)
    float* out = (float*)d_out;

    float* ws = (float*)d_ws;
    float* F = ws;                                   //     32,768 f32
    float* U = F + 32768;                            // 50,331,648 f32 (201 MB)
    float* P = U + (size_t)MROWS * KSPEC;            //  6,291,456 f32 (25 MB)
    float* z = P + (size_t)SPLITK * MROWS * DIM;     //  1,572,864 f32 (6.3 MB)

    build_filters<<<128, 256, 0, stream>>>(sigma, V, F);
    conv_kernel<<<dim3(12, 8, 64), 256, 0, stream>>>(inputs, F, U);
    gemm1_kernel<<<dim3(12, 16, SPLITK), 256, 0, stream>>>(U, inputs, Mpp, Mpm, Mu, P);
    reduce_kernel<<<1536, 256, 0, stream>>>(P, z);
    gemm2_kernel<<<dim3(6, 32), 256, 0, stream>>>(z, My, out);
}

// Round 2
// 628.184 us; speedup vs baseline: 3.3586x; 3.3586x over previous
//
#include <hip/hip_runtime.h>
#include <cstddef>
#include <cstdint>

#define SLEN 1024
#define DIM  768
#define NJ   32
#define KSPEC (NJ * DIM)          // 24576
#define KTOT  (KSPEC + 3 * DIM)   // 26880
#define MROWS (2 * SLEN)          // 2048
#define SPLITK 4
#define KT_PER_SPLIT 105          // 420 K-steps of 64 / 4 splits
#define LDA 72                    // padded LDS row stride (halfs): bank-spread + 16B aligned

typedef _Float16 f16;
typedef _Float16 f16x8 __attribute__((ext_vector_type(8)));
typedef float f32x4 __attribute__((ext_vector_type(4)));

// ---------------------------------------------------------------------------
// F32[j][tau]: j<16 -> sigma[k]^0.25 * V[tau,k]; j>=16 -> same * (-1)^tau
// block 0 also zeroes the 1KB zero-scratch used for guarded (shifted) rows.
// ---------------------------------------------------------------------------
__global__ __launch_bounds__(256) void build_filters(
    const float* __restrict__ sigma, const float* __restrict__ V,
    float* __restrict__ F, float* __restrict__ zb)
{
    int g = blockIdx.x * 256 + threadIdx.x;   // 0..32767
    if (blockIdx.x == 0) zb[threadIdx.x] = 0.f;
    int j = g >> 10, tau = g & 1023;
    int k = j & 15;
    float s = powf(sigma[k], 0.25f);
    float val = s * V[tau * 16 + k];
    if (j >= 16 && (tau & 1)) val = -val;
    F[j * SLEN + tau] = val;
}

// ---------------------------------------------------------------------------
// x (2,1024,768) f32 -> x16 [2048][768] f16 (row-major) and x16t [2][768][1024]
// ---------------------------------------------------------------------------
__global__ __launch_bounds__(256) void pack_x(
    const float* __restrict__ x, f16* __restrict__ x16, f16* __restrict__ x16t)
{
    __shared__ float tile[32][33];
    const int b  = blockIdx.z;
    const int d0 = blockIdx.y * 32;
    const int t0 = blockIdx.x * 32;
    const int tx = threadIdx.x & 31, ty = threadIdx.x >> 5;
#pragma unroll
    for (int r = 0; r < 4; ++r) {
        int tl = ty + r * 8;
        float v = x[(size_t)(b * SLEN + t0 + tl) * DIM + d0 + tx];
        tile[tl][tx] = v;
        x16[(size_t)(b * SLEN + t0 + tl) * DIM + d0 + tx] = (f16)v;
    }
    __syncthreads();
#pragma unroll
    for (int r = 0; r < 4; ++r) {
        int dl = ty + r * 8;
        x16t[((size_t)b * DIM + d0 + dl) * SLEN + t0 + tx] = (f16)tile[tx][dl];
    }
}

// ---------------------------------------------------------------------------
// W16t[o][c] = W[c][o] f16, c over [Mpp | Mpm | Mu] rows (each (k*d) x 768)
// ---------------------------------------------------------------------------
__global__ __launch_bounds__(256) void pack_w(
    const float* __restrict__ Mpp, const float* __restrict__ Mpm,
    const float* __restrict__ Mu, f16* __restrict__ W16t)
{
    __shared__ float tile[32][33];
    const int c0 = blockIdx.x * 32;
    const int o0 = blockIdx.y * 32;
    const int tx = threadIdx.x & 31, ty = threadIdx.x >> 5;
#pragma unroll
    for (int r = 0; r < 4; ++r) {
        int cl = ty + r * 8;
        int c = c0 + cl;
        const float* src;
        if (c < 12288)      src = Mpp + (size_t)c * DIM;
        else if (c < KSPEC) src = Mpm + (size_t)(c - 12288) * DIM;
        else                src = Mu  + (size_t)(c - KSPEC) * DIM;
        tile[cl][tx] = src[o0 + tx];
    }
    __syncthreads();
#pragma unroll
    for (int r = 0; r < 4; ++r) {
        int ol = ty + r * 8;
        W16t[(size_t)(o0 + ol) * KTOT + c0 + tx] = (f16)tile[tx][ol];
    }
}

// ---------------------------------------------------------------------------
// conv: U[b,l,j*768+d] = sum_{t<=l} F[j][l-t] * x[b,t,d], via MFMA.
// Block = (d-tile 128, l-tile 128, b*32+j). A (Toeplitz) fragments built in
// registers from reversed F segment in LDS; B from x16t via LDS.
// ---------------------------------------------------------------------------
__global__ __launch_bounds__(256) void conv_mfma(
    const f16* __restrict__ xt, const float* __restrict__ F,
    f16* __restrict__ U16)
{
    __shared__ f16 Bs[128 * LDA];
    __shared__ float Frv[192];
    const int d0 = blockIdx.x * 128;
    const int l0 = blockIdx.y * 128;
    const int b  = blockIdx.z >> 5;
    const int j  = blockIdx.z & 31;
    const int tid = threadIdx.x;
    const int lane = tid & 63, w = tid >> 6;
    const int wr = w >> 1, wc = w & 1;
    const int lrow = lane & 15, lgrp = lane >> 4;

    f32x4 acc[4][4];
#pragma unroll
    for (int mi = 0; mi < 4; ++mi)
#pragma unroll
        for (int ni = 0; ni < 4; ++ni) acc[mi][ni] = (f32x4){0.f, 0.f, 0.f, 0.f};

    const float* Fj = F + j * SLEN;
    const f16* xbase = xt + ((size_t)b * DIM + d0) * SLEN;
    const int srow = w * 8 + (lane >> 3);       // staging row within 32-row group
    const int scol = (lane & 7) * 8;            // staging col (halfs)
    const int nkt = (l0 >> 6) + 2;

    for (int kt = 0; kt < nkt; ++kt) {
        const int t0 = kt * 64;
        const int D = l0 - t0;
        if (tid < 192) {                        // Frv[i] = F[j][D+127-i] (reversed seg)
            int v = D + 127 - tid;
            Frv[tid] = (v >= 0) ? Fj[v] : 0.f;
        }
#pragma unroll
        for (int q = 0; q < 4; ++q) {           // Bs[d_local][t_local], padded stride
            int r = q * 32 + srow;
            uint4 v = *(const uint4*)(xbase + (size_t)r * SLEN + t0 + scol);
            *(uint4*)&Bs[r * LDA + scol] = v;
        }
        __syncthreads();
#pragma unroll
        for (int ks = 0; ks < 2; ++ks) {
            const int k0 = ks * 32 + lgrp * 8;
            f16x8 af[4];
#pragma unroll
            for (int mi = 0; mi < 4; ++mi) {
                int row = wr * 64 + mi * 16 + lrow;
                int base = 127 - row + k0;      // A[row][k0+e] = Frv[127-row+k0+e]
                f16x8 a;
#pragma unroll
                for (int e = 0; e < 8; ++e) a[e] = (f16)Frv[base + e];
                af[mi] = a;
            }
            f16x8 bf[4];
#pragma unroll
            for (int ni = 0; ni < 4; ++ni) {
                int col = wc * 64 + ni * 16 + lrow;
                bf[ni] = *(const f16x8*)&Bs[col * LDA + k0];
            }
#pragma unroll
            for (int mi = 0; mi < 4; ++mi)
#pragma unroll
                for (int ni = 0; ni < 4; ++ni)
                    acc[mi][ni] = __builtin_amdgcn_mfma_f32_16x16x32_f16(
                        af[mi], bf[ni], acc[mi][ni], 0, 0, 0);
        }
        __syncthreads();
    }
    const size_t ub = (size_t)b * SLEN * KSPEC + (size_t)j * DIM;
#pragma unroll
    for (int mi = 0; mi < 4; ++mi)
#pragma unroll
        for (int ni = 0; ni < 4; ++ni) {
            int l = l0 + wr * 64 + mi * 16 + lgrp * 4;
            int d = d0 + wc * 64 + ni * 16 + lrow;
#pragma unroll
            for (int q = 0; q < 4; ++q)
                U16[ub + (size_t)(l + q) * KSPEC + d] = (f16)acc[mi][ni][q];
        }
}

// ---------------------------------------------------------------------------
// gemm1 (MFMA fp16, split-K=4): P[s][m][o] partial of X[m][c] * W[c][o]
//  X rows: spectral from U16 (shift 2), ar_u taps from x16 (shift i); guarded
//  rows redirect the load to a zeroed scratch row (zb16).
// ---------------------------------------------------------------------------
__global__ __launch_bounds__(256) void gemm1_mfma(
    const f16* __restrict__ U16, const f16* __restrict__ x16,
    const f16* __restrict__ W16t, const f16* __restrict__ zb16,
    float* __restrict__ P)
{
    __shared__ f16 As[128 * LDA];
    __shared__ f16 Bs[128 * LDA];
    const int n0 = blockIdx.x * 128;
    const int m0 = blockIdx.y * 128;
    const int s  = blockIdx.z;
    const int tid = threadIdx.x;
    const int lane = tid & 63, w = tid >> 6;
    const int wr = w >> 1, wc = w & 1;
    const int lrow = lane & 15, lgrp = lane >> 4;

    f32x4 acc[4][4];
#pragma unroll
    for (int mi = 0; mi < 4; ++mi)
#pragma unroll
        for (int ni = 0; ni < 4; ++ni) acc[mi][ni] = (f32x4){0.f, 0.f, 0.f, 0.f};

    const int srow = w * 8 + (lane >> 3);
    const int scol = (lane & 7) * 8;

    const int kt_end = (s + 1) * KT_PER_SPLIT;
    for (int kt = s * KT_PER_SPLIT; kt < kt_end; ++kt) {
        const int c0 = kt * 64;
#pragma unroll
        for (int q = 0; q < 4; ++q) {
            int r = q * 32 + srow;
            int m = m0 + r;
            int l = m & (SLEN - 1);
            const f16* src;
            if (c0 < KSPEC) {
                src = (l >= 2) ? U16 + (size_t)(m - 2) * KSPEC + c0 + scol : zb16;
            } else {
                int i  = (c0 - KSPEC) / DIM;
                int co = c0 - KSPEC - i * DIM;
                src = (l >= i) ? x16 + (size_t)(m - i) * DIM + co + scol : zb16;
            }
            uint4 v = *(const uint4*)src;
            *(uint4*)&As[r * LDA + scol] = v;
        }
#pragma unroll
        for (int q = 0; q < 4; ++q) {
            int r = q * 32 + srow;
            uint4 v = *(const uint4*)(W16t + (size_t)(n0 + r) * KTOT + c0 + scol);
            *(uint4*)&Bs[r * LDA + scol] = v;
        }
        __syncthreads();
#pragma unroll
        for (int ks = 0; ks < 2; ++ks) {
            const int k0 = ks * 32 + lgrp * 8;
            f16x8 af[4], bf[4];
#pragma unroll
            for (int mi = 0; mi < 4; ++mi)
                af[mi] = *(const f16x8*)&As[(wr * 64 + mi * 16 + lrow) * LDA + k0];
#pragma unroll
            for (int ni = 0; ni < 4; ++ni)
                bf[ni] = *(const f16x8*)&Bs[(wc * 64 + ni * 16 + lrow) * LDA + k0];
#pragma unroll
            for (int mi = 0; mi < 4; ++mi)
#pragma unroll
                for (int ni = 0; ni < 4; ++ni)
                    acc[mi][ni] = __builtin_amdgcn_mfma_f32_16x16x32_f16(
                        af[mi], bf[ni], acc[mi][ni], 0, 0, 0);
        }
        __syncthreads();
    }
    float* Pp = P + (size_t)s * MROWS * DIM;
#pragma unroll
    for (int mi = 0; mi < 4; ++mi)
#pragma unroll
        for (int ni = 0; ni < 4; ++ni) {
            int m = m0 + wr * 64 + mi * 16 + lgrp * 4;
            int col = n0 + wc * 64 + ni * 16 + lrow;
#pragma unroll
            for (int q = 0; q < 4; ++q)
                Pp[(size_t)(m + q) * DIM + col] = acc[mi][ni][q];
        }
}

// z = sum of 4 split-K partials (deterministic)
__global__ __launch_bounds__(256) void reduce_kernel(
    const float* __restrict__ P, float* __restrict__ z)
{
    int g = blockIdx.x * 256 + threadIdx.x;   // 0..393215 float4s
    const float4* P4 = (const float4*)P;
    float4 a = P4[g];
    float4 b = P4[g + 393216];
    float4 c = P4[g + 786432];
    float4 d = P4[g + 1179648];
    ((float4*)z)[g] = make_float4(a.x + b.x + c.x + d.x,
                                  a.y + b.y + c.y + d.y,
                                  a.z + b.z + c.z + d.z,
                                  a.w + b.w + c.w + d.w);
}

// ---------------------------------------------------------------------------
// gemm2 (fp32 VALU): out[m][o] = z[m][o] + sum_{i=0,1} z[m-1-i][:] . M_y[o][i][:]
// ---------------------------------------------------------------------------
__global__ __launch_bounds__(256) void gemm2_kernel(
    const float* __restrict__ z, const float* __restrict__ My,
    float* __restrict__ out)
{
    __shared__ float As[64][20];
    __shared__ float Bs[16][128];
    const int n0 = blockIdx.x * 128;
    const int m0 = blockIdx.y * 64;
    const int tid = threadIdx.x;
    const int td = tid & 15, tl = tid >> 4;

    float acc[4][8];
#pragma unroll
    for (int i = 0; i < 4; ++i)
#pragma unroll
        for (int q = 0; q < 8; ++q) acc[i][q] = 0.f;

    const int ar = tid >> 2;
    const int ac = (tid & 3) * 4;
    const int m  = m0 + ar;
    const int l  = m & (SLEN - 1);
    const int bcc = tid & 15;
    const int bo  = (tid >> 4) * 8;

    for (int c0 = 0; c0 < 1536; c0 += 16) {
        int i = (c0 >= DIM) ? 1 : 0;
        float4 a0 = make_float4(0.f, 0.f, 0.f, 0.f);
        if (l >= i + 1)
            a0 = *(const float4*)&z[(size_t)(m - 1 - i) * DIM + (c0 - i * DIM) + ac];
        *(float4*)&As[ar][ac] = a0;
#pragma unroll
        for (int u = 0; u < 8; ++u)
            Bs[bcc][bo + u] = My[(size_t)(n0 + bo + u) * 1536 + c0 + bcc];
        __syncthreads();
#pragma unroll
        for (int kk = 0; kk < 16; ++kk) {
            float a[4];
#pragma unroll
            for (int i2 = 0; i2 < 4; ++i2) a[i2] = As[tl * 4 + i2][kk];
            float4 b0 = *(float4*)&Bs[kk][td * 8];
            float4 b1 = *(float4*)&Bs[kk][td * 8 + 4];
#pragma unroll
            for (int i2 = 0; i2 < 4; ++i2) {
                acc[i2][0] = fmaf(a[i2], b0.x, acc[i2][0]);
                acc[i2][1] = fmaf(a[i2], b0.y, acc[i2][1]);
                acc[i2][2] = fmaf(a[i2], b0.z, acc[i2][2]);
                acc[i2][3] = fmaf(a[i2], b0.w, acc[i2][3]);
                acc[i2][4] = fmaf(a[i2], b1.x, acc[i2][4]);
                acc[i2][5] = fmaf(a[i2], b1.y, acc[i2][5]);
                acc[i2][6] = fmaf(a[i2], b1.z, acc[i2][6]);
                acc[i2][7] = fmaf(a[i2], b1.w, acc[i2][7]);
            }
        }
        __syncthreads();
    }
#pragma unroll
    for (int i = 0; i < 4; ++i) {
        int mm = m0 + tl * 4 + i;
        const float* zr = z + (size_t)mm * DIM + n0 + td * 8;
        float4 z0 = *(const float4*)zr;
        float4 z1 = *(const float4*)(zr + 4);
        float* orow = out + (size_t)mm * DIM + n0 + td * 8;
        *(float4*)orow =
            make_float4(acc[i][0] + z0.x, acc[i][1] + z0.y,
                        acc[i][2] + z0.z, acc[i][3] + z0.w);
        *(float4*)(orow + 4) =
            make_float4(acc[i][4] + z1.x, acc[i][5] + z1.y,
                        acc[i][6] + z1.z, acc[i][7] + z1.w);
    }
}

extern "C" void kernel_launch(void* const* d_in, const int* in_sizes, int n_in,
                              void* d_out, int out_size, void* d_ws, size_t ws_size,
                              hipStream_t stream)
{
    const float* inputs = (const float*)d_in[0];   // (2,1024,768)
    const float* sigma  = (const float*)d_in[1];   // (16,)
    const float* V      = (const float*)d_in[2];   // (1024,16)
    const float* Mu     = (const float*)d_in[3];   // (3,768,768)
    const float* Mpp    = (const float*)d_in[4];   // (16,768,768)
    const float* Mpm    = (const float*)d_in[5];   // (16,768,768)
    const float* My     = (const float*)d_in[6];   // (768,2,768)
    float* out = (float*)d_out;

    float* F32 = (float*)d_ws;                       //   131072 B
    float* zb  = F32 + 32768;                        //     1024 B (zeroed)
    f16* x16   = (f16*)(zb + 256);                   //  3145728 B
    f16* x16t  = x16 + (size_t)MROWS * DIM;          //  3145728 B
    f16* W16t  = x16t + (size_t)MROWS * DIM;         // 41287680 B
    f16* U16   = W16t + (size_t)DIM * KTOT;          // 100663296 B
    float* P   = (float*)(U16 + (size_t)MROWS * KSPEC); // 25165824 B
    float* z   = P + (size_t)SPLITK * MROWS * DIM;   //  6291456 B

    build_filters<<<128, 256, 0, stream>>>(sigma, V, F32, zb);
    pack_x<<<dim3(32, 24, 2), 256, 0, stream>>>(inputs, x16, x16t);
    pack_w<<<dim3(840, 24), 256, 0, stream>>>(Mpp, Mpm, Mu, W16t);
    conv_mfma<<<dim3(6, 8, 64), 256, 0, stream>>>(x16t, F32, U16);
    gemm1_mfma<<<dim3(6, 16, SPLITK), 256, 0, stream>>>(U16, x16, W16t, (const f16*)zb, P);
    reduce_kernel<<<1536, 256, 0, stream>>>(P, z);
    gemm2_kernel<<<dim3(6, 32), 256, 0, stream>>>(z, My, out);
}

// Round 5
// 390.699 us; speedup vs baseline: 5.4001x; 1.6078x over previous
//
#include <hip/hip_runtime.h>
#include <cstddef>
#include <cstdint>

#define SLEN 1024
#define DIM  768
#define NJ   32
#define KSPEC (NJ * DIM)          // 24576
#define KTOT  (KSPEC + 3 * DIM)   // 26880
#define MROWS (2 * SLEN)          // 2048
#define SK1 8                     // gemm1 split-K (420 K-steps -> 52/53 each)
#define SK2 4                     // gemm2 split-K (24 K-steps -> 6 each)

typedef _Float16 f16;
typedef _Float16 f16x8 __attribute__((ext_vector_type(8)));
typedef _Float16 f16x4 __attribute__((ext_vector_type(4)));
typedef float    f32x4 __attribute__((ext_vector_type(4)));

// async global->LDS, 16B per lane. LDS dest = wave-uniform base + lane*16.
__device__ __forceinline__ void async16(f16* lds, const f16* g) {
    __builtin_amdgcn_global_load_lds(
        (const __attribute__((address_space(1))) unsigned int*)g,
        (__attribute__((address_space(3))) unsigned int*)lds, 16, 0, 0);
}

// ---------------------------------------------------------------------------
// R8[j][i] (i in [0,1536)): reversed, zero-padded filter table (f16).
// R8[j][i] = F[j][1031-i] for 8<=i<1032, else 0.  F[j][tau] = sigma^0.25 * V
// with (-1)^tau folded for j>=16.  Also zeroes the 1KB zb scratch.
// ---------------------------------------------------------------------------
__global__ __launch_bounds__(256) void build_r8(
    const float* __restrict__ sigma, const float* __restrict__ V,
    f16* __restrict__ R8, float* __restrict__ zb)
{
    int g = blockIdx.x * 256 + threadIdx.x;   // 0..49151
    if (g < 256) zb[g] = 0.f;
    int j = g / 1536, i = g % 1536;
    int k = j & 15;
    int tau = 1031 - i;
    float val = 0.f;
    if (tau >= 0 && tau < 1024) {
        val = powf(sigma[k], 0.25f) * V[tau * 16 + k];
        if (j >= 16 && (tau & 1)) val = -val;
    }
    R8[j * 1536 + i] = (f16)val;
}

// ---------------------------------------------------------------------------
// x (2,1024,768) f32 -> x16 [2048][768] f16 and x16t [2][768][1024] f16
// ---------------------------------------------------------------------------
__global__ __launch_bounds__(256) void pack_x(
    const float* __restrict__ x, f16* __restrict__ x16, f16* __restrict__ x16t)
{
    __shared__ float tile[32][33];
    const int b  = blockIdx.z;
    const int d0 = blockIdx.y * 32;
    const int t0 = blockIdx.x * 32;
    const int tx = threadIdx.x & 31, ty = threadIdx.x >> 5;
#pragma unroll
    for (int r = 0; r < 4; ++r) {
        int tl = ty + r * 8;
        float v = x[(size_t)(b * SLEN + t0 + tl) * DIM + d0 + tx];
        tile[tl][tx] = v;
        x16[(size_t)(b * SLEN + t0 + tl) * DIM + d0 + tx] = (f16)v;
    }
    __syncthreads();
#pragma unroll
    for (int r = 0; r < 4; ++r) {
        int dl = ty + r * 8;
        x16t[((size_t)b * DIM + d0 + dl) * SLEN + t0 + tx] = (f16)tile[tx][dl];
    }
}

// ---------------------------------------------------------------------------
// W16t[o][c] = W[c][o] f16, c over [Mpp | Mpm | Mu]
// ---------------------------------------------------------------------------
__global__ __launch_bounds__(256) void pack_w(
    const float* __restrict__ Mpp, const float* __restrict__ Mpm,
    const float* __restrict__ Mu, f16* __restrict__ W16t)
{
    __shared__ float tile[32][33];
    const int c0 = blockIdx.x * 32;
    const int o0 = blockIdx.y * 32;
    const int tx = threadIdx.x & 31, ty = threadIdx.x >> 5;
#pragma unroll
    for (int r = 0; r < 4; ++r) {
        int cl = ty + r * 8;
        int c = c0 + cl;
        const float* src;
        if (c < 12288)      src = Mpp + (size_t)c * DIM;
        else if (c < KSPEC) src = Mpm + (size_t)(c - 12288) * DIM;
        else                src = Mu  + (size_t)(c - KSPEC) * DIM;
        tile[cl][tx] = src[o0 + tx];
    }
    __syncthreads();
#pragma unroll
    for (int r = 0; r < 4; ++r) {
        int ol = ty + r * 8;
        W16t[(size_t)(o0 + ol) * KTOT + c0 + tx] = (f16)tile[tx][ol];
    }
}

// My (768,2,768) f32 -> f16 elementwise: My16t[o][c] with c = i*768+d
__global__ __launch_bounds__(256) void pack_my(
    const float* __restrict__ My, f16* __restrict__ My16t)
{
    int g = blockIdx.x * 256 + threadIdx.x;   // 0..294911 float4s
    float4 v = ((const float4*)My)[g];
    f16x4 h = {(f16)v.x, (f16)v.y, (f16)v.z, (f16)v.w};
    ((f16x4*)My16t)[g] = h;
}

// ---------------------------------------------------------------------------
// conv: U[b,l,j*768+d] = sum_{t<=l} F[j][l-t] * x[b,t,d]  via MFMA.
// A (Toeplitz) read from 8 shift-aligned copies of the reversed filter seg:
//   Cp[c][jj] = R8j[(904-D) + jj - c]  =>  A-frag = aligned b128 at c*265+h.
// B from x16t via global_load_lds with XOR-swizzled source / swizzled read.
// ---------------------------------------------------------------------------
__global__ __launch_bounds__(256) void conv_mfma(
    const f16* __restrict__ xt, const f16* __restrict__ R8,
    f16* __restrict__ U16)
{
    __shared__ f16 Bs[128 * 64];
    __shared__ f16 Cp[8 * 264];
    const int d0 = blockIdx.x * 128;
    const int l0 = blockIdx.y * 128;
    const int b  = blockIdx.z >> 5;
    const int j  = blockIdx.z & 31;
    const int tid = threadIdx.x;
    const int lane = tid & 63, w = tid >> 6;
    const int wr = w >> 1, wc = w & 1;
    const int lrow = lane & 15, lgrp = lane >> 4;
    const int rrel = lane >> 3, slotw = lane & 7;
    const int colh = (slotw ^ rrel) * 8;      // pre-swizzled source col (halfs)

    f32x4 acc[4][4];
#pragma unroll
    for (int mi = 0; mi < 4; ++mi)
#pragma unroll
        for (int ni = 0; ni < 4; ++ni) acc[mi][ni] = (f32x4){0.f, 0.f, 0.f, 0.f};

    const f16* R8j = R8 + j * 1536;
    const f16* xb  = xt + ((size_t)b * DIM + d0) * SLEN;
    const int cch = tid / 33;                 // copy id for build chunk
    const int cjc = (tid % 33) * 8;           // within-copy offset (halfs)
    const int nkt = (l0 >> 6) + 2;

    for (int kt = 0; kt < nkt; ++kt) {
        const int t0 = kt * 64;
        const int base = 904 - l0 + t0;       // 904 - D, D = l0 - t0
        // build 8 shifted copies (2112 halfs) from L2-hot R8j
        {
            const f16* gp = R8j + base + cjc - cch;
            f16x8 v;
#pragma unroll
            for (int e = 0; e < 8; ++e) v[e] = gp[e];
            *(f16x8*)&Cp[cch * 264 + cjc] = v;
            if (tid < 8) {
                int ch2 = tid + 256;
                int c2 = ch2 / 33, jc2 = (ch2 % 33) * 8;
                const f16* gp2 = R8j + base + jc2 - c2;
                f16x8 v2;
#pragma unroll
                for (int e = 0; e < 8; ++e) v2[e] = gp2[e];
                *(f16x8*)&Cp[c2 * 264 + jc2] = v2;
            }
        }
#pragma unroll
        for (int q = 0; q < 4; ++q) {
            int row = w * 32 + q * 8 + rrel;
            async16(&Bs[(w * 32 + q * 8) * 64],
                    xb + (size_t)row * SLEN + t0 + colh);
        }
        __syncthreads();
#pragma unroll
        for (int ks = 0; ks < 2; ++ks) {
            f16x8 af[4], bf[4];
#pragma unroll
            for (int mi = 0; mi < 4; ++mi) {
                int r = wr * 64 + mi * 16 + lrow;
                int h = 127 - r + ks * 32 + lgrp * 8;
                int c = (-h) & 7;
                af[mi] = *(const f16x8*)&Cp[c * 265 + h];   // c*264 + (h+c)
            }
#pragma unroll
            for (int ni = 0; ni < 4; ++ni) {
                int col = wc * 64 + ni * 16 + lrow;
                int slot = (ks * 4 + lgrp) ^ (col & 7);
                bf[ni] = *(const f16x8*)&Bs[col * 64 + slot * 8];
            }
#pragma unroll
            for (int mi = 0; mi < 4; ++mi)
#pragma unroll
                for (int ni = 0; ni < 4; ++ni)
                    acc[mi][ni] = __builtin_amdgcn_mfma_f32_16x16x32_f16(
                        af[mi], bf[ni], acc[mi][ni], 0, 0, 0);
        }
        __syncthreads();
    }
    const size_t ub = (size_t)b * SLEN * KSPEC + (size_t)j * DIM;
#pragma unroll
    for (int mi = 0; mi < 4; ++mi)
#pragma unroll
        for (int ni = 0; ni < 4; ++ni) {
            int l = l0 + wr * 64 + mi * 16 + lgrp * 4;
            int d = d0 + wc * 64 + ni * 16 + lrow;
#pragma unroll
            for (int q = 0; q < 4; ++q)
                U16[ub + (size_t)(l + q) * KSPEC + d] = (f16)acc[mi][ni][q];
        }
}

// ---------------------------------------------------------------------------
// gemm1 (fp16 MFMA, split-K=8): P[s][m][o] partial of X[m][c]*W[c][o]
// A/B staged with global_load_lds (linear LDS; source pre-XOR-swizzled;
// ds_read applies slot ^ (row&7)). Guarded rows redirect source to zb.
// ---------------------------------------------------------------------------
__global__ __launch_bounds__(256) void gemm1_mfma(
    const f16* __restrict__ U16, const f16* __restrict__ x16,
    const f16* __restrict__ W16t, const f16* __restrict__ zb16,
    float* __restrict__ P)
{
    __shared__ f16 As[128 * 64];
    __shared__ f16 Bs[128 * 64];
    const int n0 = blockIdx.x * 128;
    const int m0 = blockIdx.y * 128;
    const int s  = blockIdx.z;
    const int tid = threadIdx.x;
    const int lane = tid & 63, w = tid >> 6;
    const int wr = w >> 1, wc = w & 1;
    const int lrow = lane & 15, lgrp = lane >> 4;
    const int rrel = lane >> 3, slotw = lane & 7;
    const int colh = (slotw ^ rrel) * 8;

    f32x4 acc[4][4];
#pragma unroll
    for (int mi = 0; mi < 4; ++mi)
#pragma unroll
        for (int ni = 0; ni < 4; ++ni) acc[mi][ni] = (f32x4){0.f, 0.f, 0.f, 0.f};

    const int kts = (420 * s) >> 3, kte = (420 * (s + 1)) >> 3;
    for (int kt = kts; kt < kte; ++kt) {
        const int c0 = kt * 64;
#pragma unroll
        for (int q = 0; q < 4; ++q) {
            int row = w * 32 + q * 8 + rrel;
            int m = m0 + row;
            int l = m & (SLEN - 1);
            const f16* src;
            if (c0 < KSPEC) {
                src = (l >= 2) ? U16 + (size_t)(m - 2) * KSPEC + c0 + colh : zb16;
            } else {
                int cr = c0 - KSPEC;
                int i  = cr / DIM;            // tile-uniform tap
                src = (l >= i) ? x16 + (size_t)(m - i) * DIM + (cr - i * DIM) + colh
                               : zb16;
            }
            async16(&As[(w * 32 + q * 8) * 64], src);
        }
#pragma unroll
        for (int q = 0; q < 4; ++q) {
            int row = w * 32 + q * 8 + rrel;
            async16(&Bs[(w * 32 + q * 8) * 64],
                    W16t + (size_t)(n0 + row) * KTOT + c0 + colh);
        }
        __syncthreads();
#pragma unroll
        for (int ks = 0; ks < 2; ++ks) {
            f16x8 af[4], bf[4];
#pragma unroll
            for (int mi = 0; mi < 4; ++mi) {
                int r = wr * 64 + mi * 16 + lrow;
                int slot = (ks * 4 + lgrp) ^ (r & 7);
                af[mi] = *(const f16x8*)&As[r * 64 + slot * 8];
            }
#pragma unroll
            for (int ni = 0; ni < 4; ++ni) {
                int col = wc * 64 + ni * 16 + lrow;
                int slot = (ks * 4 + lgrp) ^ (col & 7);
                bf[ni] = *(const f16x8*)&Bs[col * 64 + slot * 8];
            }
#pragma unroll
            for (int mi = 0; mi < 4; ++mi)
#pragma unroll
                for (int ni = 0; ni < 4; ++ni)
                    acc[mi][ni] = __builtin_amdgcn_mfma_f32_16x16x32_f16(
                        af[mi], bf[ni], acc[mi][ni], 0, 0, 0);
        }
        __syncthreads();
    }
    float* Pp = P + (size_t)s * MROWS * DIM;
#pragma unroll
    for (int mi = 0; mi < 4; ++mi)
#pragma unroll
        for (int ni = 0; ni < 4; ++ni) {
            int m = m0 + wr * 64 + mi * 16 + lgrp * 4;
            int col = n0 + wc * 64 + ni * 16 + lrow;
#pragma unroll
            for (int q = 0; q < 4; ++q)
                Pp[(size_t)(m + q) * DIM + col] = acc[mi][ni][q];
        }
}

// z = sum of 8 split-K partials; also emit z16 (f16) for gemm2
__global__ __launch_bounds__(256) void reduce8(
    const float* __restrict__ P, float* __restrict__ z, f16* __restrict__ z16)
{
    int g = blockIdx.x * 256 + threadIdx.x;   // 0..393215 float4s
    const float4* P4 = (const float4*)P;
    float4 s = P4[g];
#pragma unroll
    for (int i = 1; i < SK1; ++i) {
        float4 t = P4[g + (size_t)i * 393216];
        s.x += t.x; s.y += t.y; s.z += t.z; s.w += t.w;
    }
    ((float4*)z)[g] = s;
    f16x4 h = {(f16)s.x, (f16)s.y, (f16)s.z, (f16)s.w};
    ((f16x4*)z16)[g] = h;
}

// ---------------------------------------------------------------------------
// gemm2 (fp16 MFMA, split-K=4): P2[s][m][o] partial of
//   sum_{i=0,1} z[m-1-i][d] * My[o][i*768+d]
// ---------------------------------------------------------------------------
__global__ __launch_bounds__(256) void gemm2_mfma(
    const f16* __restrict__ z16, const f16* __restrict__ My16t,
    const f16* __restrict__ zb16, float* __restrict__ P2)
{
    __shared__ f16 As[128 * 64];
    __shared__ f16 Bs[128 * 64];
    const int n0 = blockIdx.x * 128;
    const int m0 = blockIdx.y * 128;
    const int s  = blockIdx.z;
    const int tid = threadIdx.x;
    const int lane = tid & 63, w = tid >> 6;
    const int wr = w >> 1, wc = w & 1;
    const int lrow = lane & 15, lgrp = lane >> 4;
    const int rrel = lane >> 3, slotw = lane & 7;
    const int colh = (slotw ^ rrel) * 8;

    f32x4 acc[4][4];
#pragma unroll
    for (int mi = 0; mi < 4; ++mi)
#pragma unroll
        for (int ni = 0; ni < 4; ++ni) acc[mi][ni] = (f32x4){0.f, 0.f, 0.f, 0.f};

    for (int kt = s * 6; kt < (s + 1) * 6; ++kt) {
        const int c0 = kt * 64;
        const int i = (c0 >= DIM) ? 1 : 0;    // tile-uniform tap
        const int sh = i + 1;
        const int co = c0 - i * DIM;
#pragma unroll
        for (int q = 0; q < 4; ++q) {
            int row = w * 32 + q * 8 + rrel;
            int m = m0 + row;
            int l = m & (SLEN - 1);
            const f16* src = (l >= sh)
                ? z16 + (size_t)(m - sh) * DIM + co + colh : zb16;
            async16(&As[(w * 32 + q * 8) * 64], src);
        }
#pragma unroll
        for (int q = 0; q < 4; ++q) {
            int row = w * 32 + q * 8 + rrel;
            async16(&Bs[(w * 32 + q * 8) * 64],
                    My16t + (size_t)(n0 + row) * 1536 + c0 + colh);
        }
        __syncthreads();
#pragma unroll
        for (int ks = 0; ks < 2; ++ks) {
            f16x8 af[4], bf[4];
#pragma unroll
            for (int mi = 0; mi < 4; ++mi) {
                int r = wr * 64 + mi * 16 + lrow;
                int slot = (ks * 4 + lgrp) ^ (r & 7);
                af[mi] = *(const f16x8*)&As[r * 64 + slot * 8];
            }
#pragma unroll
            for (int ni = 0; ni < 4; ++ni) {
                int col = wc * 64 + ni * 16 + lrow;
                int slot = (ks * 4 + lgrp) ^ (col & 7);
                bf[ni] = *(const f16x8*)&Bs[col * 64 + slot * 8];
            }
#pragma unroll
            for (int mi = 0; mi < 4; ++mi)
#pragma unroll
                for (int ni = 0; ni < 4; ++ni)
                    acc[mi][ni] = __builtin_amdgcn_mfma_f32_16x16x32_f16(
                        af[mi], bf[ni], acc[mi][ni], 0, 0, 0);
        }
        __syncthreads();
    }
    float* Pp = P2 + (size_t)s * MROWS * DIM;
#pragma unroll
    for (int mi = 0; mi < 4; ++mi)
#pragma unroll
        for (int ni = 0; ni < 4; ++ni) {
            int m = m0 + wr * 64 + mi * 16 + lgrp * 4;
            int col = n0 + wc * 64 + ni * 16 + lrow;
#pragma unroll
            for (int q = 0; q < 4; ++q)
                Pp[(size_t)(m + q) * DIM + col] = acc[mi][ni][q];
        }
}

// out = z + sum of 4 gemm2 partials
__global__ __launch_bounds__(256) void final_add(
    const float* __restrict__ z, const float* __restrict__ P2,
    float* __restrict__ out)
{
    int g = blockIdx.x * 256 + threadIdx.x;   // 0..393215 float4s
    const float4* z4 = (const float4*)z;
    const float4* Q  = (const float4*)P2;
    float4 s = z4[g];
#pragma unroll
    for (int i = 0; i < SK2; ++i) {
        float4 t = Q[g + (size_t)i * 393216];
        s.x += t.x; s.y += t.y; s.z += t.z; s.w += t.w;
    }
    ((float4*)out)[g] = s;
}

extern "C" void kernel_launch(void* const* d_in, const int* in_sizes, int n_in,
                              void* d_out, int out_size, void* d_ws, size_t ws_size,
                              hipStream_t stream)
{
    const float* inputs = (const float*)d_in[0];   // (2,1024,768)
    const float* sigma  = (const float*)d_in[1];   // (16,)
    const float* V      = (const float*)d_in[2];   // (1024,16)
    const float* Mu     = (const float*)d_in[3];   // (3,768,768)
    const float* Mpp    = (const float*)d_in[4];   // (16,768,768)
    const float* Mpm    = (const float*)d_in[5];   // (16,768,768)
    const float* My     = (const float*)d_in[6];   // (768,2,768)
    float* out = (float*)d_out;

    char* base = (char*)d_ws;
    float* zb   = (float*)(base);                  // 1 KB zeros
    f16* R8     = (f16*)(base + 1024);             // 96 KB
    f16* x16    = (f16*)(base + 99328);            // 3 MB
    f16* x16t   = (f16*)(base + 3245056);          // 3 MB
    f16* W16t   = (f16*)(base + 6390784);          // 41 MB
    f16* My16t  = (f16*)(base + 47678464);         // 2.3 MB
    f16* U16    = (f16*)(base + 50037760);         // 100 MB
    f16* z16    = (f16*)(base + 150701056);        // 3 MB
    float* P    = (float*)(base + 153846784);      // 50 MB (P2 aliases split 0-3)
    float* z    = (float*)(base + 204178432);      // 6 MB
    const f16* zb16 = (const f16*)zb;

    build_r8<<<192, 256, 0, stream>>>(sigma, V, R8, zb);
    pack_x<<<dim3(32, 24, 2), 256, 0, stream>>>(inputs, x16, x16t);
    pack_w<<<dim3(840, 24), 256, 0, stream>>>(Mpp, Mpm, Mu, W16t);
    pack_my<<<1152, 256, 0, stream>>>(My, My16t);
    conv_mfma<<<dim3(6, 8, 64), 256, 0, stream>>>(x16t, R8, U16);
    gemm1_mfma<<<dim3(6, 16, SK1), 256, 0, stream>>>(U16, x16, W16t, zb16, P);
    reduce8<<<1536, 256, 0, stream>>>(P, z, z16);
    gemm2_mfma<<<dim3(6, 16, SK2), 256, 0, stream>>>(z16, My16t, zb16, P);
    final_add<<<1536, 256, 0, stream>>>(z, P, out);
}